// Round 3
// baseline (760.778 us; speedup 1.0000x reference)
//
#include <hip/hip_runtime.h>
#include <hip/hip_bf16.h>

// MoE expert MLP, grouped-GEMM formulation:
//   - all operands pre-converted to bf16 (chunked weight scratch reused on-stream)
//   - GEMMs: 256x128 tile, 8 waves, BK=64, 3-slot LDS ring (144 KB) with
//     counted vmcnt(12) (T3+T4: loads in flight across raw s_barriers, never
//     drained to 0 in the main loop), setprio around MFMA clusters (T5)
//   - global_load_lds width=16 staging, 8-quad XOR swizzle (qslot = q^(row&7))
//     -> conflict-free ds_read_b128 (verified: SQ_LDS_BANK_CONFLICT = 0)
//   - sigma B-row permutation: each lane owns 4 contiguous output columns
//   - r3 SCHEDULE FIX (fabric-BW theory): r2 measured 7.6 TB/s of beyond-L2
//     staging traffic (1.77 GB/dispatch, FETCH 391 MB vs 80 MB unique) with
//     MfmaUtil stuck at 26% under two different pipeline depths -> L2 reuse,
//     not latency, is the lever.
//     * gemm1: grid flipped to (cb fastest, tile slow): XCD = cb%8, resident
//       set per XCD = 8 tiles x 4 cbs rectangle -> A tile fetched once per
//       XCD (shared by 4 cbs), B panel shared by 8 consecutive tiles (same
//       expert). Beyond-L2 ~1.77 GB -> ~0.4 GB.
//     * gemm2: custom static-tile map (A = Hbuf = 134 MB dominant operand):
//       XCD x owns tiles [9x,9x+9) x all 8 cbs; resident = 4 tiles x 8 cbs
//       -> each Hbuf tile fetched ONCE device-wide. Beyond-L2 ~1.3 -> ~0.2 GB.
//   - NO atomics: gemm2 stores to pair-indexed Yp, combine applies topk weights

#define SS 8192
#define HD 1024
#define FD 4096
#define NE 8
#define TK 2
#define NP (SS * TK)
#define T256 (NP / 256 + NE)   // 72 max 256-row tiles (divisible by 8)
#define TPX (T256 / 8)         // 9 tiles per XCD (gemm2 static partition)

#define SLOT_B 49152           // 48 KB per ring slot (A 32 KB + B 16 KB)
#define RING_B (3 * SLOT_B)    // 144 KB

typedef __bf16 bf16x8 __attribute__((ext_vector_type(8)));
typedef unsigned short us8 __attribute__((ext_vector_type(8)));
typedef float f32x4 __attribute__((ext_vector_type(4)));
typedef unsigned int u32;

static __device__ __forceinline__ unsigned short f2bf(float f) {
  union { float f; unsigned u; } v; v.f = f;
  return (unsigned short)((v.u + 0x7fffu + ((v.u >> 16) & 1u)) >> 16);  // RNE
}

static __device__ __forceinline__ bf16x8 frag_ld(const unsigned short* p) {
  union { us8 u; bf16x8 b; } v;
  v.u = *(const us8*)p;
  return v.b;
}

static __device__ __forceinline__ void gll16(const void* g, void* l) {
  __builtin_amdgcn_global_load_lds(
      (const __attribute__((address_space(1))) u32*)g,
      (__attribute__((address_space(3))) u32*)l, 16, 0, 0);
}

static __device__ __forceinline__ float silu(float v) {
  return v / (1.f + __expf(-v));
}

// sigma: B-row permutation within each 64-row half: sigma(h*64+16q+l) = h*64+4l+q
static __device__ __forceinline__ int sigma(int r) {
  return (r & 64) + ((r & 15) * 4) + ((r >> 4) & 3);
}

#define MEMFENCE asm volatile("" ::: "memory")

// ---------------- bucket building ----------------

__global__ void count_kernel(const int* __restrict__ topk_e, int* __restrict__ counts) {
  __shared__ int lc[NE];
  int tid = threadIdx.x;
  if (tid < NE) lc[tid] = 0;
  __syncthreads();
  atomicAdd(&lc[topk_e[blockIdx.x * 256 + tid]], 1);
  __syncthreads();
  if (tid < NE) atomicAdd(&counts[tid], lc[tid]);
}

__global__ void plan_kernel(const int* __restrict__ counts, int* __restrict__ offsets,
                            int* __restrict__ cursors, int* __restrict__ tile_expert,
                            int* __restrict__ tile_rowstart, int* __restrict__ total_tiles) {
  if (threadIdx.x != 0 || blockIdx.x != 0) return;
  int off = 0, tt = 0;
  for (int e = 0; e < NE; ++e) {
    offsets[e] = off;
    cursors[e] = off;
    int n = counts[e];
    int nt = (n + 255) >> 8;
    for (int i = 0; i < nt; ++i) {
      tile_expert[tt] = e;
      tile_rowstart[tt] = off + i * 256;
      ++tt;
    }
    off += n;
  }
  offsets[NE] = off;
  *total_tiles = tt;
}

__global__ void scatter_kernel(const int* __restrict__ topk_e, const float* __restrict__ topk_w,
                               int* __restrict__ cursors, int* __restrict__ row_token,
                               int* __restrict__ inv) {
  __shared__ int lcnt[NE];
  __shared__ int lbase[NE];
  int tid = threadIdx.x;
  if (tid < NE) lcnt[tid] = 0;
  __syncthreads();
  int t = blockIdx.x * 256 + tid;
  int e = topk_e[t];
  int my = atomicAdd(&lcnt[e], 1);
  __syncthreads();
  if (tid < NE) lbase[tid] = atomicAdd(&cursors[tid], lcnt[tid]);
  __syncthreads();
  int pos = lbase[e] + my;
  row_token[pos] = t / TK;
  inv[t] = pos;
}

// ---------------- fp32 -> bf16 converts ----------------

__global__ void conv_x_kernel(const float* __restrict__ x, unsigned short* __restrict__ xb) {
  int i = blockIdx.x * 256 + threadIdx.x;      // one thread per 8 floats
  const float4* s = (const float4*)(x + (size_t)i * 8);
  float4 a = s[0], b = s[1];
  us8 o = {f2bf(a.x), f2bf(a.y), f2bf(a.z), f2bf(a.w),
           f2bf(b.x), f2bf(b.y), f2bf(b.z), f2bf(b.w)};
  *(us8*)(xb + (size_t)i * 8) = o;
}

// w1 chunk: [E][FC][HD], source rows contiguous per expert
__global__ void conv_w1c_kernel(const float* __restrict__ w1, unsigned short* __restrict__ wc,
                                int c, int FC) {
  int i = blockIdx.x * 256 + threadIdx.x;
  int per_e = FC * HD;
  int pos = i * 8;
  int e = pos / per_e;
  int rem = pos - e * per_e;
  const float4* s = (const float4*)(w1 + ((size_t)e * FD + (size_t)c * FC) * HD + rem);
  float4 a = s[0], b = s[1];
  us8 o = {f2bf(a.x), f2bf(a.y), f2bf(a.z), f2bf(a.w),
           f2bf(b.x), f2bf(b.y), f2bf(b.z), f2bf(b.w)};
  *(us8*)(wc + (size_t)pos) = o;
}

// w2 chunk: [E][HD][FC], source is an F-slice of each row
__global__ void conv_w2c_kernel(const float* __restrict__ w2, unsigned short* __restrict__ wc,
                                int c, int FC) {
  int i = blockIdx.x * 256 + threadIdx.x;
  int per_e = HD * FC;
  int pos = i * 8;
  int e = pos / per_e;
  int rem = pos - e * per_e;
  int h = rem / FC;
  int f0 = rem - h * FC;
  const float4* s = (const float4*)(w2 + ((size_t)e * HD + h) * FD + (size_t)c * FC + f0);
  float4 a = s[0], b = s[1];
  us8 o = {f2bf(a.x), f2bf(a.y), f2bf(a.z), f2bf(a.w),
           f2bf(b.x), f2bf(b.y), f2bf(b.z), f2bf(b.w)};
  *(us8*)(wc + (size_t)pos) = o;
}

// ---------------- GEMM1: Hc = silu(Xg @ W1c^T) ----------------
// 256x128 tile, BK=64, 3-slot ring, counted vmcnt(12), raw barriers.
// LDS slot layout (48 KB): A rows 0..255 at r*128B (slot s holds quad q^(r&7)
// at 16B-slot q), then B rows 0..127 at 32768 + r*128B.
// Grid: dim3(FC/128 [cb, fastest], T256 [tile]) -> XCD = cb%8; resident set
// per XCD = 8 tiles x 4 cbs rectangle (A fetched once/XCD, B panel shared by
// the 8 consecutive same-expert tiles).

__global__ __launch_bounds__(512, 2) void gemm1_kernel(
    const unsigned short* __restrict__ xb, const unsigned short* __restrict__ w1c,
    const int* __restrict__ row_token, const int* __restrict__ offsets,
    const int* __restrict__ tile_expert, const int* __restrict__ tile_rowstart,
    const int* __restrict__ total_tiles,
    unsigned short* __restrict__ Hbuf, int FC) {
  int rt = blockIdx.y;
  if (rt >= *total_tiles) return;
  int e = tile_expert[rt];
  int rstart = tile_rowstart[rt];
  int nvalid = offsets[e + 1] - rstart;
  if (nvalid > 256) nvalid = 256;
  int fb = blockIdx.x * 128;

  __shared__ alignas(16) char smem[RING_B];

  int tid = threadIdx.x, lane = tid & 63, wv = tid >> 6;
  int qel = ((lane & 7) ^ ((lane >> 3) & 7)) * 8;   // source k-quad (elements)

  // A: 4 stage ops x (8 waves x 8 rows); B: 2 stage ops
  const unsigned short* ag[4];
  const unsigned short* bg[2];
#pragma unroll
  for (int p = 0; p < 4; ++p) {
    int r = p * 64 + wv * 8 + (lane >> 3);
    int rg = rstart + r;
    if (rg > NP - 1) rg = NP - 1;
    ag[p] = xb + (size_t)row_token[rg] * HD + qel;
  }
#pragma unroll
  for (int p = 0; p < 2; ++p) {
    int r = p * 64 + wv * 8 + (lane >> 3);
    bg[p] = w1c + ((size_t)e * FC + fb + sigma(r)) * HD + qel;
  }

  f32x4 acc[4][4];
  f32x4 vz = {0.f, 0.f, 0.f, 0.f};
#pragma unroll
  for (int i = 0; i < 4; ++i)
#pragma unroll
    for (int j = 0; j < 4; ++j) acc[i][j] = vz;

  int wm = (wv & 3) * 64, wn = (wv >> 2) * 64;
  int lr = lane & 15;

  auto STAGE = [&](int kk, int slotb) {
    char* db = smem + slotb + wv * 1024;
    int kof = kk * 64;
#pragma unroll
    for (int p = 0; p < 4; ++p) gll16(ag[p] + kof, db + p * 8192);
#pragma unroll
    for (int p = 0; p < 2; ++p) gll16(bg[p] + kof, db + 32768 + p * 8192);
  };

  const int NT = HD / 64;   // 16
  STAGE(0, 0);
  STAGE(1, SLOT_B);
  int rslot = 0, wslot = 2 * SLOT_B;

  for (int t = 0; t < NT; ++t) {
    int kk = t + 2; if (kk >= NT) kk = NT - 1;   // dummy re-stage keeps vmcnt uniform
    STAGE(kk, wslot);
    asm volatile("s_waitcnt vmcnt(12)" ::: "memory");
    __builtin_amdgcn_s_barrier();
    MEMFENCE;
    const unsigned short* As = (const unsigned short*)(smem + rslot);
    const unsigned short* Bs = As + 16384;
#pragma unroll
    for (int tt = 0; tt < 2; ++tt) {
      int qsl = ((tt * 4 + (lane >> 4)) ^ (lr & 7)) * 8;
      bf16x8 af[4], bfr[4];
#pragma unroll
      for (int i = 0; i < 4; ++i) af[i] = frag_ld(&As[(wm + i * 16 + lr) * 64 + qsl]);
#pragma unroll
      for (int j = 0; j < 4; ++j) bfr[j] = frag_ld(&Bs[(wn + j * 16 + lr) * 64 + qsl]);
      __builtin_amdgcn_s_setprio(1);
#pragma unroll
      for (int i = 0; i < 4; ++i)
#pragma unroll
        for (int j = 0; j < 4; ++j)
          acc[i][j] = __builtin_amdgcn_mfma_f32_16x16x32_bf16(af[i], bfr[j], acc[i][j], 0, 0, 0);
      __builtin_amdgcn_s_setprio(0);
    }
    MEMFENCE;
    __builtin_amdgcn_s_barrier();
    rslot += SLOT_B; if (rslot >= RING_B) rslot = 0;
    wslot += SLOT_B; if (wslot >= RING_B) wslot = 0;
  }
  asm volatile("s_waitcnt vmcnt(0)" ::: "memory");

  // epilogue: lane owns 4 contiguous cols (sigma permutation) -> ushort4 stores
  int cbc = wn + (lane & 15) * 4;
  int rq = (lane >> 4) * 4;
#pragma unroll
  for (int i = 0; i < 4; ++i) {
#pragma unroll
    for (int r = 0; r < 4; ++r) {
      int row = wm + i * 16 + rq + r;
      if (row < nvalid) {
        ushort4 hv;
        hv.x = f2bf(silu(acc[i][0][r]));
        hv.y = f2bf(silu(acc[i][1][r]));
        hv.z = f2bf(silu(acc[i][2][r]));
        hv.w = f2bf(silu(acc[i][3][r]));
        *(ushort4*)&Hbuf[(size_t)(rstart + row) * FC + fb + cbc] = hv;
      }
    }
  }
}

// ---------------- GEMM2: Yp = Hc @ W2c^T (pair rows, no weights, no atomics) ----------------
// 1D grid of T256*8 blocks. Static tile partition: XCD x = b%8 owns tiles
// [TPX*x, TPX*(x+1)) x all 8 hb's; within an XCD, hb varies fastest so the
// resident 32 blocks = 4 tiles x 8 hb -> each 2 MB Hbuf tile is fetched once
// device-wide and reused by all 8 hb blocks from the XCD's L2.

__global__ __launch_bounds__(512, 2) void gemm2_kernel(
    const unsigned short* __restrict__ Hbuf, const unsigned short* __restrict__ w2c,
    const int* __restrict__ offsets,
    const int* __restrict__ tile_expert, const int* __restrict__ tile_rowstart,
    const int* __restrict__ total_tiles,
    float* __restrict__ Yp, int FC, int first) {
  int b = blockIdx.x;
  int xcd = b & 7, j = b >> 3;          // j in [0, T256)
  int cb = j & 7, tloc = j >> 3;        // tloc in [0, TPX)
  int rt = xcd * TPX + tloc;
  if (rt >= *total_tiles) return;
  int e = tile_expert[rt];
  int rstart = tile_rowstart[rt];
  int nvalid = offsets[e + 1] - rstart;
  if (nvalid > 256) nvalid = 256;
  int hb = cb * 128;

  __shared__ alignas(16) char smem[RING_B];

  int tid = threadIdx.x, lane = tid & 63, wv = tid >> 6;
  int qel = ((lane & 7) ^ ((lane >> 3) & 7)) * 8;

  const unsigned short* ag[4];
  const unsigned short* bg[2];
#pragma unroll
  for (int p = 0; p < 4; ++p) {
    int r = p * 64 + wv * 8 + (lane >> 3);
    int rg = rstart + r;
    if (rg > NP - 1) rg = NP - 1;
    ag[p] = Hbuf + (size_t)rg * FC + qel;
  }
#pragma unroll
  for (int p = 0; p < 2; ++p) {
    int r = p * 64 + wv * 8 + (lane >> 3);
    bg[p] = w2c + ((size_t)e * HD + hb + sigma(r)) * FC + qel;
  }

  f32x4 acc[4][4];
  f32x4 vz = {0.f, 0.f, 0.f, 0.f};
#pragma unroll
  for (int i = 0; i < 4; ++i)
#pragma unroll
    for (int j2 = 0; j2 < 4; ++j2) acc[i][j2] = vz;

  int wm = (wv & 3) * 64, wn = (wv >> 2) * 64;
  int lr = lane & 15;

  auto STAGE = [&](int kk, int slotb) {
    char* db = smem + slotb + wv * 1024;
    int kof = kk * 64;
#pragma unroll
    for (int p = 0; p < 4; ++p) gll16(ag[p] + kof, db + p * 8192);
#pragma unroll
    for (int p = 0; p < 2; ++p) gll16(bg[p] + kof, db + 32768 + p * 8192);
  };

  const int NT = FC / 64;
  STAGE(0, 0);
  STAGE(1, SLOT_B);
  int rslot = 0, wslot = 2 * SLOT_B;

  for (int t = 0; t < NT; ++t) {
    int kk = t + 2; if (kk >= NT) kk = NT - 1;
    STAGE(kk, wslot);
    asm volatile("s_waitcnt vmcnt(12)" ::: "memory");
    __builtin_amdgcn_s_barrier();
    MEMFENCE;
    const unsigned short* As = (const unsigned short*)(smem + rslot);
    const unsigned short* Bs = As + 16384;
#pragma unroll
    for (int tt = 0; tt < 2; ++tt) {
      int qsl = ((tt * 4 + (lane >> 4)) ^ (lr & 7)) * 8;
      bf16x8 af[4], bfr[4];
#pragma unroll
      for (int i = 0; i < 4; ++i) af[i] = frag_ld(&As[(wm + i * 16 + lr) * 64 + qsl]);
#pragma unroll
      for (int j2 = 0; j2 < 4; ++j2) bfr[j2] = frag_ld(&Bs[(wn + j2 * 16 + lr) * 64 + qsl]);
      __builtin_amdgcn_s_setprio(1);
#pragma unroll
      for (int i = 0; i < 4; ++i)
#pragma unroll
        for (int j2 = 0; j2 < 4; ++j2)
          acc[i][j2] = __builtin_amdgcn_mfma_f32_16x16x32_bf16(af[i], bfr[j2], acc[i][j2], 0, 0, 0);
      __builtin_amdgcn_s_setprio(0);
    }
    MEMFENCE;
    __builtin_amdgcn_s_barrier();
    rslot += SLOT_B; if (rslot >= RING_B) rslot = 0;
    wslot += SLOT_B; if (wslot >= RING_B) wslot = 0;
  }
  asm volatile("s_waitcnt vmcnt(0)" ::: "memory");

  int cbc = wn + (lane & 15) * 4;
  int rq = (lane >> 4) * 4;
#pragma unroll
  for (int i = 0; i < 4; ++i) {
#pragma unroll
    for (int r = 0; r < 4; ++r) {
      int row = wm + i * 16 + rq + r;
      if (row < nvalid) {
        float* dst = Yp + (size_t)(rstart + row) * HD + hb + cbc;
        float4 v;
        v.x = acc[i][0][r]; v.y = acc[i][1][r]; v.z = acc[i][2][r]; v.w = acc[i][3][r];
        if (!first) {
          float4 o = *(const float4*)dst;
          v.x += o.x; v.y += o.y; v.z += o.z; v.w += o.w;
        }
        *(float4*)dst = v;
      }
    }
  }
}

// ---------------- combine: y[s] = sum_k topk_w[s,k] * Yp[inv[s*2+k]] ----------------

__global__ void combine_kernel(const float* __restrict__ Yp, const int* __restrict__ inv,
                               const float* __restrict__ topk_w, float* __restrict__ y) {
  int s = blockIdx.x;
  int c = threadIdx.x * 4;
  int i0 = inv[s * 2], i1 = inv[s * 2 + 1];
  float w0 = topk_w[s * 2], w1 = topk_w[s * 2 + 1];
  float4 a = *(const float4*)(Yp + (size_t)i0 * HD + c);
  float4 b = *(const float4*)(Yp + (size_t)i1 * HD + c);
  float4 o;
  o.x = w0 * a.x + w1 * b.x;
  o.y = w0 * a.y + w1 * b.y;
  o.z = w0 * a.z + w1 * b.z;
  o.w = w0 * a.w + w1 * b.w;
  *(float4*)(y + (size_t)s * HD + c) = o;
}

// ---------------- host ----------------

extern "C" void kernel_launch(void* const* d_in, const int* in_sizes, int n_in,
                              void* d_out, int out_size, void* d_ws, size_t ws_size,
                              hipStream_t stream) {
  const float* x      = (const float*)d_in[0];
  const int*   topk_e = (const int*)d_in[1];
  const float* topk_w = (const float*)d_in[2];
  const float* w1     = (const float*)d_in[3];
  const float* w2     = (const float*)d_in[4];
  float* y = (float*)d_out;

  char* ws = (char*)d_ws;
  int* counts        = (int*)(ws + 0);
  int* cursors       = (int*)(ws + 64);
  int* offsets       = (int*)(ws + 128);
  int* total_tiles   = (int*)(ws + 192);
  int* tile_expert   = (int*)(ws + 256);
  int* tile_rowstart = (int*)(ws + 1024);
  int* row_token     = (int*)(ws + 4096);
  int* inv           = (int*)(ws + 4096 + (size_t)NP * 4);
  size_t hdr = 4096 + (size_t)NP * 8;

  unsigned short* xb = (unsigned short*)(ws + hdr);
  size_t xbytes = (size_t)SS * HD * 2;
  size_t ypbytes = (size_t)NP * HD * 4;

  // largest F-chunk whose (weight scratch + bf16 H buffer + Yp) fits
  int FC = FD;
  while (FC > 256) {
    size_t need = hdr + xbytes + (size_t)NE * FC * HD * 2 + (size_t)NP * FC * 2 + ypbytes;
    if (need <= ws_size) break;
    FC >>= 1;
  }
  unsigned short* wc = xb + (size_t)SS * HD;
  unsigned short* Hbuf = wc + (size_t)NE * FC * HD;
  float* Yp = (float*)(Hbuf + (size_t)NP * FC);

  hipMemsetAsync(d_ws, 0, 2048, stream);

  count_kernel<<<NP / 256, 256, 0, stream>>>(topk_e, counts);
  plan_kernel<<<1, 1, 0, stream>>>(counts, offsets, cursors, tile_expert, tile_rowstart, total_tiles);
  scatter_kernel<<<NP / 256, 256, 0, stream>>>(topk_e, topk_w, cursors, row_token, inv);
  conv_x_kernel<<<SS * HD / 8 / 256, 256, 0, stream>>>(x, xb);

  int nchunks = FD / FC;
  int wblocks = (int)((size_t)NE * FC * HD / 8 / 256);
  for (int c = 0; c < nchunks; ++c) {
    conv_w1c_kernel<<<wblocks, 256, 0, stream>>>(w1, wc, c, FC);
    gemm1_kernel<<<dim3(FC / 128, T256), 512, 0, stream>>>(
        xb, wc, row_token, offsets, tile_expert, tile_rowstart, total_tiles, Hbuf, FC);
    // wc is free again once gemm1 completes (stream-ordered): reuse for w2 chunk
    conv_w2c_kernel<<<wblocks, 256, 0, stream>>>(w2, wc, c, FC);
    gemm2_kernel<<<T256 * (HD / 128), 512, 0, stream>>>(
        Hbuf, wc, offsets, tile_expert, tile_rowstart, total_tiles, Yp, FC, c == 0 ? 1 : 0);
  }
  combine_kernel<<<SS, 256, 0, stream>>>(Yp, inv, topk_w, y);
}

// Round 4
// 732.509 us; speedup vs baseline: 1.0386x; 1.0386x over previous
//
#include <hip/hip_runtime.h>
#include <hip/hip_bf16.h>

// MoE expert MLP, grouped-GEMM formulation:
//   - all operands pre-converted to bf16 (chunked weight scratch reused on-stream)
//   - GEMMs: 256x128 tile, 8 waves, BK=64, 3-slot LDS ring (144 KB)
//   - r4: 8-phase-style PER-PHASE ENGINE (T3+T4 fine interleave, m196/m201/m248):
//     each K-tile = 2 phases of {8 ds_read + 3 global_load_lds -> s_barrier ->
//     lgkmcnt(0) -> setprio(1) 16xMFMA setprio(0) -> s_barrier}; vmcnt(6)
//     counted ONCE per K-tile (never 0 in the loop): tile t+1's staging is
//     ordered before its reads by [vmcnt(6) .. barrier .. reads] across waves.
//     r1/r2/r3 proved the kernel is NOT HBM/L2/latency-bound (FETCH 436->178MB
//     with dur unchanged, 15-16 cyc/MFMA across 3 schedules) -> the interleave
//     structure is the remaining lever per the regime-gate evidence.
//   - global_load_lds width=16 staging, 8-quad XOR swizzle (qslot = q^(row&7))
//     -> conflict-free ds_read_b128 (verified: SQ_LDS_BANK_CONFLICT = 0)
//   - sigma B-row permutation: each lane owns 4 contiguous output columns
//   - r3 XCD-partitioned grids kept (gemm2 FETCH 178 MB ~= unique set)
//   - NO atomics: gemm2 stores to pair-indexed Yp, combine applies topk weights

#define SS 8192
#define HD 1024
#define FD 4096
#define NE 8
#define TK 2
#define NP (SS * TK)
#define T256 (NP / 256 + NE)   // 72 max 256-row tiles (divisible by 8)
#define TPX (T256 / 8)         // 9 tiles per XCD (gemm2 static partition)

#define SLOT_B 49152           // 48 KB per ring slot (A 32 KB + B 16 KB)
#define RING_B (3 * SLOT_B)    // 144 KB

typedef __bf16 bf16x8 __attribute__((ext_vector_type(8)));
typedef unsigned short us8 __attribute__((ext_vector_type(8)));
typedef float f32x4 __attribute__((ext_vector_type(4)));
typedef unsigned int u32;

static __device__ __forceinline__ unsigned short f2bf(float f) {
  union { float f; unsigned u; } v; v.f = f;
  return (unsigned short)((v.u + 0x7fffu + ((v.u >> 16) & 1u)) >> 16);  // RNE
}

static __device__ __forceinline__ bf16x8 frag_ld(const unsigned short* p) {
  union { us8 u; bf16x8 b; } v;
  v.u = *(const us8*)p;
  return v.b;
}

static __device__ __forceinline__ void gll16(const void* g, void* l) {
  __builtin_amdgcn_global_load_lds(
      (const __attribute__((address_space(1))) u32*)g,
      (__attribute__((address_space(3))) u32*)l, 16, 0, 0);
}

static __device__ __forceinline__ float silu(float v) {
  return v / (1.f + __expf(-v));
}

// sigma: B-row permutation within each 64-row half: sigma(h*64+16q+l) = h*64+4l+q
static __device__ __forceinline__ int sigma(int r) {
  return (r & 64) + ((r & 15) * 4) + ((r >> 4) & 3);
}

#define MEMFENCE asm volatile("" ::: "memory")

// ---------------- bucket building ----------------

__global__ void count_kernel(const int* __restrict__ topk_e, int* __restrict__ counts) {
  __shared__ int lc[NE];
  int tid = threadIdx.x;
  if (tid < NE) lc[tid] = 0;
  __syncthreads();
  atomicAdd(&lc[topk_e[blockIdx.x * 256 + tid]], 1);
  __syncthreads();
  if (tid < NE) atomicAdd(&counts[tid], lc[tid]);
}

__global__ void plan_kernel(const int* __restrict__ counts, int* __restrict__ offsets,
                            int* __restrict__ cursors, int* __restrict__ tile_expert,
                            int* __restrict__ tile_rowstart, int* __restrict__ total_tiles) {
  if (threadIdx.x != 0 || blockIdx.x != 0) return;
  int off = 0, tt = 0;
  for (int e = 0; e < NE; ++e) {
    offsets[e] = off;
    cursors[e] = off;
    int n = counts[e];
    int nt = (n + 255) >> 8;
    for (int i = 0; i < nt; ++i) {
      tile_expert[tt] = e;
      tile_rowstart[tt] = off + i * 256;
      ++tt;
    }
    off += n;
  }
  offsets[NE] = off;
  *total_tiles = tt;
}

__global__ void scatter_kernel(const int* __restrict__ topk_e, const float* __restrict__ topk_w,
                               int* __restrict__ cursors, int* __restrict__ row_token,
                               int* __restrict__ inv) {
  __shared__ int lcnt[NE];
  __shared__ int lbase[NE];
  int tid = threadIdx.x;
  if (tid < NE) lcnt[tid] = 0;
  __syncthreads();
  int t = blockIdx.x * 256 + tid;
  int e = topk_e[t];
  int my = atomicAdd(&lcnt[e], 1);
  __syncthreads();
  if (tid < NE) lbase[tid] = atomicAdd(&cursors[tid], lcnt[tid]);
  __syncthreads();
  int pos = lbase[e] + my;
  row_token[pos] = t / TK;
  inv[t] = pos;
}

// ---------------- fp32 -> bf16 converts ----------------

__global__ void conv_x_kernel(const float* __restrict__ x, unsigned short* __restrict__ xb) {
  int i = blockIdx.x * 256 + threadIdx.x;      // one thread per 8 floats
  const float4* s = (const float4*)(x + (size_t)i * 8);
  float4 a = s[0], b = s[1];
  us8 o = {f2bf(a.x), f2bf(a.y), f2bf(a.z), f2bf(a.w),
           f2bf(b.x), f2bf(b.y), f2bf(b.z), f2bf(b.w)};
  *(us8*)(xb + (size_t)i * 8) = o;
}

// w1 chunk: [E][FC][HD], source rows contiguous per expert
__global__ void conv_w1c_kernel(const float* __restrict__ w1, unsigned short* __restrict__ wc,
                                int c, int FC) {
  int i = blockIdx.x * 256 + threadIdx.x;
  int per_e = FC * HD;
  int pos = i * 8;
  int e = pos / per_e;
  int rem = pos - e * per_e;
  const float4* s = (const float4*)(w1 + ((size_t)e * FD + (size_t)c * FC) * HD + rem);
  float4 a = s[0], b = s[1];
  us8 o = {f2bf(a.x), f2bf(a.y), f2bf(a.z), f2bf(a.w),
           f2bf(b.x), f2bf(b.y), f2bf(b.z), f2bf(b.w)};
  *(us8*)(wc + (size_t)pos) = o;
}

// w2 chunk: [E][HD][FC], source is an F-slice of each row
__global__ void conv_w2c_kernel(const float* __restrict__ w2, unsigned short* __restrict__ wc,
                                int c, int FC) {
  int i = blockIdx.x * 256 + threadIdx.x;
  int per_e = HD * FC;
  int pos = i * 8;
  int e = pos / per_e;
  int rem = pos - e * per_e;
  int h = rem / FC;
  int f0 = rem - h * FC;
  const float4* s = (const float4*)(w2 + ((size_t)e * HD + h) * FD + (size_t)c * FC + f0);
  float4 a = s[0], b = s[1];
  us8 o = {f2bf(a.x), f2bf(a.y), f2bf(a.z), f2bf(a.w),
           f2bf(b.x), f2bf(b.y), f2bf(b.z), f2bf(b.w)};
  *(us8*)(wc + (size_t)pos) = o;
}

// ---------------- GEMM1: Hc = silu(Xg @ W1c^T) ----------------
// 256x128 tile, BK=64, 3-slot ring, per-phase engine.
// LDS slot layout (48 KB): A rows 0..255 at r*128B (slot s holds quad q^(r&7)
// at 16B-slot q), then B rows 0..127 at 32768 + r*128B.
// Grid: dim3(FC/128 [cb, fastest], T256 [tile]).

__global__ __launch_bounds__(512, 2) void gemm1_kernel(
    const unsigned short* __restrict__ xb, const unsigned short* __restrict__ w1c,
    const int* __restrict__ row_token, const int* __restrict__ offsets,
    const int* __restrict__ tile_expert, const int* __restrict__ tile_rowstart,
    const int* __restrict__ total_tiles,
    unsigned short* __restrict__ Hbuf, int FC) {
  int rt = blockIdx.y;
  if (rt >= *total_tiles) return;
  int e = tile_expert[rt];
  int rstart = tile_rowstart[rt];
  int nvalid = offsets[e + 1] - rstart;
  if (nvalid > 256) nvalid = 256;
  int fb = blockIdx.x * 128;

  __shared__ alignas(16) char smem[RING_B];

  int tid = threadIdx.x, lane = tid & 63, wv = tid >> 6;
  int qel = ((lane & 7) ^ ((lane >> 3) & 7)) * 8;   // source k-quad (elements)

  const unsigned short* ag[4];
  const unsigned short* bg[2];
#pragma unroll
  for (int p = 0; p < 4; ++p) {
    int r = p * 64 + wv * 8 + (lane >> 3);
    int rg = rstart + r;
    if (rg > NP - 1) rg = NP - 1;
    ag[p] = xb + (size_t)row_token[rg] * HD + qel;
  }
#pragma unroll
  for (int p = 0; p < 2; ++p) {
    int r = p * 64 + wv * 8 + (lane >> 3);
    bg[p] = w1c + ((size_t)e * FC + fb + sigma(r)) * HD + qel;
  }

  f32x4 acc[4][4];
  f32x4 vz = {0.f, 0.f, 0.f, 0.f};
#pragma unroll
  for (int i = 0; i < 4; ++i)
#pragma unroll
    for (int j = 0; j < 4; ++j) acc[i][j] = vz;

  int wm = (wv & 3) * 64, wn = (wv >> 2) * 64;
  int lr = lane & 15;

  auto STAGE_H1 = [&](int kk, int slotb) {   // 3 loads: A rows 0..127 + B rows 0..63
    char* db = smem + slotb + wv * 1024;
    int kof = kk * 64;
    gll16(ag[0] + kof, db);
    gll16(ag[1] + kof, db + 8192);
    gll16(bg[0] + kof, db + 32768);
  };
  auto STAGE_H2 = [&](int kk, int slotb) {   // 3 loads: A rows 128..255 + B rows 64..127
    char* db = smem + slotb + wv * 1024;
    int kof = kk * 64;
    gll16(ag[2] + kof, db + 16384);
    gll16(ag[3] + kof, db + 24576);
    gll16(bg[1] + kof, db + 32768 + 8192);
  };

  const int NT = HD / 64;   // 16
  STAGE_H1(0, 0); STAGE_H2(0, 0);
  STAGE_H1(1, SLOT_B); STAGE_H2(1, SLOT_B);
  asm volatile("s_waitcnt vmcnt(6)" ::: "memory");   // tile 0 landed (tile 1 in flight)
  __builtin_amdgcn_s_barrier();
  int rslot = 0, wslot = 2 * SLOT_B;

  for (int t = 0; t < NT; ++t) {
    int kk = t + 2; if (kk >= NT) kk = NT - 1;   // dummy re-stage keeps vmcnt uniform
    const unsigned short* As = (const unsigned short*)(smem + rslot);
    const unsigned short* Bs = As + 16384;
    // ---------- phase 1: k-half 0 ----------
    MEMFENCE;
    {
      int qsl = ((lane >> 4) ^ (lr & 7)) * 8;
      bf16x8 af[4], bfr[4];
#pragma unroll
      for (int i = 0; i < 4; ++i) af[i] = frag_ld(&As[(wm + i * 16 + lr) * 64 + qsl]);
#pragma unroll
      for (int j = 0; j < 4; ++j) bfr[j] = frag_ld(&Bs[(wn + j * 16 + lr) * 64 + qsl]);
      STAGE_H1(kk, wslot);
      __builtin_amdgcn_s_barrier();
      asm volatile("s_waitcnt lgkmcnt(0)" ::: "memory");
      __builtin_amdgcn_sched_barrier(0);
      __builtin_amdgcn_s_setprio(1);
#pragma unroll
      for (int i = 0; i < 4; ++i)
#pragma unroll
        for (int j = 0; j < 4; ++j)
          acc[i][j] = __builtin_amdgcn_mfma_f32_16x16x32_bf16(af[i], bfr[j], acc[i][j], 0, 0, 0);
      __builtin_amdgcn_s_setprio(0);
    }
    MEMFENCE;
    __builtin_amdgcn_s_barrier();
    // ---------- phase 2: k-half 1 ----------
    MEMFENCE;
    {
      int qsl = ((4 + (lane >> 4)) ^ (lr & 7)) * 8;
      bf16x8 af[4], bfr[4];
#pragma unroll
      for (int i = 0; i < 4; ++i) af[i] = frag_ld(&As[(wm + i * 16 + lr) * 64 + qsl]);
#pragma unroll
      for (int j = 0; j < 4; ++j) bfr[j] = frag_ld(&Bs[(wn + j * 16 + lr) * 64 + qsl]);
      STAGE_H2(kk, wslot);
      asm volatile("s_waitcnt vmcnt(6)" ::: "memory");  // tile t+1 landed; t+2 in flight
      __builtin_amdgcn_s_barrier();
      asm volatile("s_waitcnt lgkmcnt(0)" ::: "memory");
      __builtin_amdgcn_sched_barrier(0);
      __builtin_amdgcn_s_setprio(1);
#pragma unroll
      for (int i = 0; i < 4; ++i)
#pragma unroll
        for (int j = 0; j < 4; ++j)
          acc[i][j] = __builtin_amdgcn_mfma_f32_16x16x32_bf16(af[i], bfr[j], acc[i][j], 0, 0, 0);
      __builtin_amdgcn_s_setprio(0);
    }
    MEMFENCE;
    __builtin_amdgcn_s_barrier();
    rslot += SLOT_B; if (rslot >= RING_B) rslot = 0;
    wslot += SLOT_B; if (wslot >= RING_B) wslot = 0;
  }
  asm volatile("s_waitcnt vmcnt(0)" ::: "memory");

  // epilogue: lane owns 4 contiguous cols (sigma permutation) -> ushort4 stores
  int cbc = wn + (lane & 15) * 4;
  int rq = (lane >> 4) * 4;
#pragma unroll
  for (int i = 0; i < 4; ++i) {
#pragma unroll
    for (int r = 0; r < 4; ++r) {
      int row = wm + i * 16 + rq + r;
      if (row < nvalid) {
        ushort4 hv;
        hv.x = f2bf(silu(acc[i][0][r]));
        hv.y = f2bf(silu(acc[i][1][r]));
        hv.z = f2bf(silu(acc[i][2][r]));
        hv.w = f2bf(silu(acc[i][3][r]));
        *(ushort4*)&Hbuf[(size_t)(rstart + row) * FC + fb + cbc] = hv;
      }
    }
  }
}

// ---------------- GEMM2: Yp = Hc @ W2c^T (pair rows, no weights, no atomics) ----------------
// Same phase engine. 1D grid, static XCD partition (r3: FETCH ~= unique set).

__global__ __launch_bounds__(512, 2) void gemm2_kernel(
    const unsigned short* __restrict__ Hbuf, const unsigned short* __restrict__ w2c,
    const int* __restrict__ offsets,
    const int* __restrict__ tile_expert, const int* __restrict__ tile_rowstart,
    const int* __restrict__ total_tiles,
    float* __restrict__ Yp, int FC, int first) {
  int b = blockIdx.x;
  int xcd = b & 7, j = b >> 3;          // j in [0, T256)
  int cb = j & 7, tloc = j >> 3;        // tloc in [0, TPX)
  int rt = xcd * TPX + tloc;
  if (rt >= *total_tiles) return;
  int e = tile_expert[rt];
  int rstart = tile_rowstart[rt];
  int nvalid = offsets[e + 1] - rstart;
  if (nvalid > 256) nvalid = 256;
  int hb = cb * 128;

  __shared__ alignas(16) char smem[RING_B];

  int tid = threadIdx.x, lane = tid & 63, wv = tid >> 6;
  int qel = ((lane & 7) ^ ((lane >> 3) & 7)) * 8;

  const unsigned short* ag[4];
  const unsigned short* bg[2];
#pragma unroll
  for (int p = 0; p < 4; ++p) {
    int r = p * 64 + wv * 8 + (lane >> 3);
    int rg = rstart + r;
    if (rg > NP - 1) rg = NP - 1;
    ag[p] = Hbuf + (size_t)rg * FC + qel;
  }
#pragma unroll
  for (int p = 0; p < 2; ++p) {
    int r = p * 64 + wv * 8 + (lane >> 3);
    bg[p] = w2c + ((size_t)e * HD + hb + sigma(r)) * FC + qel;
  }

  f32x4 acc[4][4];
  f32x4 vz = {0.f, 0.f, 0.f, 0.f};
#pragma unroll
  for (int i = 0; i < 4; ++i)
#pragma unroll
    for (int j2 = 0; j2 < 4; ++j2) acc[i][j2] = vz;

  int wm = (wv & 3) * 64, wn = (wv >> 2) * 64;
  int lr = lane & 15;

  auto STAGE_H1 = [&](int kk, int slotb) {
    char* db = smem + slotb + wv * 1024;
    int kof = kk * 64;
    gll16(ag[0] + kof, db);
    gll16(ag[1] + kof, db + 8192);
    gll16(bg[0] + kof, db + 32768);
  };
  auto STAGE_H2 = [&](int kk, int slotb) {
    char* db = smem + slotb + wv * 1024;
    int kof = kk * 64;
    gll16(ag[2] + kof, db + 16384);
    gll16(ag[3] + kof, db + 24576);
    gll16(bg[1] + kof, db + 32768 + 8192);
  };

  const int NT = FC / 64;
  STAGE_H1(0, 0); STAGE_H2(0, 0);
  STAGE_H1(1, SLOT_B); STAGE_H2(1, SLOT_B);
  asm volatile("s_waitcnt vmcnt(6)" ::: "memory");
  __builtin_amdgcn_s_barrier();
  int rslot = 0, wslot = 2 * SLOT_B;

  for (int t = 0; t < NT; ++t) {
    int kk = t + 2; if (kk >= NT) kk = NT - 1;
    const unsigned short* As = (const unsigned short*)(smem + rslot);
    const unsigned short* Bs = As + 16384;
    // ---------- phase 1: k-half 0 ----------
    MEMFENCE;
    {
      int qsl = ((lane >> 4) ^ (lr & 7)) * 8;
      bf16x8 af[4], bfr[4];
#pragma unroll
      for (int i = 0; i < 4; ++i) af[i] = frag_ld(&As[(wm + i * 16 + lr) * 64 + qsl]);
#pragma unroll
      for (int j2 = 0; j2 < 4; ++j2) bfr[j2] = frag_ld(&Bs[(wn + j2 * 16 + lr) * 64 + qsl]);
      STAGE_H1(kk, wslot);
      __builtin_amdgcn_s_barrier();
      asm volatile("s_waitcnt lgkmcnt(0)" ::: "memory");
      __builtin_amdgcn_sched_barrier(0);
      __builtin_amdgcn_s_setprio(1);
#pragma unroll
      for (int i = 0; i < 4; ++i)
#pragma unroll
        for (int j2 = 0; j2 < 4; ++j2)
          acc[i][j2] = __builtin_amdgcn_mfma_f32_16x16x32_bf16(af[i], bfr[j2], acc[i][j2], 0, 0, 0);
      __builtin_amdgcn_s_setprio(0);
    }
    MEMFENCE;
    __builtin_amdgcn_s_barrier();
    // ---------- phase 2: k-half 1 ----------
    MEMFENCE;
    {
      int qsl = ((4 + (lane >> 4)) ^ (lr & 7)) * 8;
      bf16x8 af[4], bfr[4];
#pragma unroll
      for (int i = 0; i < 4; ++i) af[i] = frag_ld(&As[(wm + i * 16 + lr) * 64 + qsl]);
#pragma unroll
      for (int j2 = 0; j2 < 4; ++j2) bfr[j2] = frag_ld(&Bs[(wn + j2 * 16 + lr) * 64 + qsl]);
      STAGE_H2(kk, wslot);
      asm volatile("s_waitcnt vmcnt(6)" ::: "memory");
      __builtin_amdgcn_s_barrier();
      asm volatile("s_waitcnt lgkmcnt(0)" ::: "memory");
      __builtin_amdgcn_sched_barrier(0);
      __builtin_amdgcn_s_setprio(1);
#pragma unroll
      for (int i = 0; i < 4; ++i)
#pragma unroll
        for (int j2 = 0; j2 < 4; ++j2)
          acc[i][j2] = __builtin_amdgcn_mfma_f32_16x16x32_bf16(af[i], bfr[j2], acc[i][j2], 0, 0, 0);
      __builtin_amdgcn_s_setprio(0);
    }
    MEMFENCE;
    __builtin_amdgcn_s_barrier();
    rslot += SLOT_B; if (rslot >= RING_B) rslot = 0;
    wslot += SLOT_B; if (wslot >= RING_B) wslot = 0;
  }
  asm volatile("s_waitcnt vmcnt(0)" ::: "memory");

  int cbc = wn + (lane & 15) * 4;
  int rq = (lane >> 4) * 4;
#pragma unroll
  for (int i = 0; i < 4; ++i) {
#pragma unroll
    for (int r = 0; r < 4; ++r) {
      int row = wm + i * 16 + rq + r;
      if (row < nvalid) {
        float* dst = Yp + (size_t)(rstart + row) * HD + hb + cbc;
        float4 v;
        v.x = acc[i][0][r]; v.y = acc[i][1][r]; v.z = acc[i][2][r]; v.w = acc[i][3][r];
        if (!first) {
          float4 o = *(const float4*)dst;
          v.x += o.x; v.y += o.y; v.z += o.z; v.w += o.w;
        }
        *(float4*)dst = v;
      }
    }
  }
}

// ---------------- combine: y[s] = sum_k topk_w[s,k] * Yp[inv[s*2+k]] ----------------

__global__ void combine_kernel(const float* __restrict__ Yp, const int* __restrict__ inv,
                               const float* __restrict__ topk_w, float* __restrict__ y) {
  int s = blockIdx.x;
  int c = threadIdx.x * 4;
  int i0 = inv[s * 2], i1 = inv[s * 2 + 1];
  float w0 = topk_w[s * 2], w1 = topk_w[s * 2 + 1];
  float4 a = *(const float4*)(Yp + (size_t)i0 * HD + c);
  float4 b = *(const float4*)(Yp + (size_t)i1 * HD + c);
  float4 o;
  o.x = w0 * a.x + w1 * b.x;
  o.y = w0 * a.y + w1 * b.y;
  o.z = w0 * a.z + w1 * b.z;
  o.w = w0 * a.w + w1 * b.w;
  *(float4*)(y + (size_t)s * HD + c) = o;
}

// ---------------- host ----------------

extern "C" void kernel_launch(void* const* d_in, const int* in_sizes, int n_in,
                              void* d_out, int out_size, void* d_ws, size_t ws_size,
                              hipStream_t stream) {
  const float* x      = (const float*)d_in[0];
  const int*   topk_e = (const int*)d_in[1];
  const float* topk_w = (const float*)d_in[2];
  const float* w1     = (const float*)d_in[3];
  const float* w2     = (const float*)d_in[4];
  float* y = (float*)d_out;

  char* ws = (char*)d_ws;
  int* counts        = (int*)(ws + 0);
  int* cursors       = (int*)(ws + 64);
  int* offsets       = (int*)(ws + 128);
  int* total_tiles   = (int*)(ws + 192);
  int* tile_expert   = (int*)(ws + 256);
  int* tile_rowstart = (int*)(ws + 1024);
  int* row_token     = (int*)(ws + 4096);
  int* inv           = (int*)(ws + 4096 + (size_t)NP * 4);
  size_t hdr = 4096 + (size_t)NP * 8;

  unsigned short* xb = (unsigned short*)(ws + hdr);
  size_t xbytes = (size_t)SS * HD * 2;
  size_t ypbytes = (size_t)NP * HD * 4;

  // largest F-chunk whose (weight scratch + bf16 H buffer + Yp) fits
  int FC = FD;
  while (FC > 256) {
    size_t need = hdr + xbytes + (size_t)NE * FC * HD * 2 + (size_t)NP * FC * 2 + ypbytes;
    if (need <= ws_size) break;
    FC >>= 1;
  }
  unsigned short* wc = xb + (size_t)SS * HD;
  unsigned short* Hbuf = wc + (size_t)NE * FC * HD;
  float* Yp = (float*)(Hbuf + (size_t)NP * FC);

  hipMemsetAsync(d_ws, 0, 2048, stream);

  count_kernel<<<NP / 256, 256, 0, stream>>>(topk_e, counts);
  plan_kernel<<<1, 1, 0, stream>>>(counts, offsets, cursors, tile_expert, tile_rowstart, total_tiles);
  scatter_kernel<<<NP / 256, 256, 0, stream>>>(topk_e, topk_w, cursors, row_token, inv);
  conv_x_kernel<<<SS * HD / 8 / 256, 256, 0, stream>>>(x, xb);

  int nchunks = FD / FC;
  int wblocks = (int)((size_t)NE * FC * HD / 8 / 256);
  for (int c = 0; c < nchunks; ++c) {
    conv_w1c_kernel<<<wblocks, 256, 0, stream>>>(w1, wc, c, FC);
    gemm1_kernel<<<dim3(FC / 128, T256), 512, 0, stream>>>(
        xb, wc, row_token, offsets, tile_expert, tile_rowstart, total_tiles, Hbuf, FC);
    // wc is free again once gemm1 completes (stream-ordered): reuse for w2 chunk
    conv_w2c_kernel<<<wblocks, 256, 0, stream>>>(w2, wc, c, FC);
    gemm2_kernel<<<T256 * (HD / 128), 512, 0, stream>>>(
        Hbuf, wc, offsets, tile_expert, tile_rowstart, total_tiles, Yp, FC, c == 0 ? 1 : 0);
  }
  combine_kernel<<<SS, 256, 0, stream>>>(Yp, inv, topk_w, y);
}